// Round 7
// baseline (139.010 us; speedup 1.0000x reference)
//
#include <hip/hip_runtime.h>

#define NFULL 4096
#define CDIM  512
#define HEADS 8
#define DDIM  64

typedef unsigned short u16;
typedef short bf16x8 __attribute__((ext_vector_type(8)));
typedef float f32x4 __attribute__((ext_vector_type(4)));

#define EXP2(x) exp2f(x)

// q pre-scaled by SCALE * log2(e) so exp(s) == exp2(s').
#define QSCALE 11.541560327111707f  // 8 * 1.4426950408889634

__device__ __forceinline__ float dot4(float4 a, float4 b) {
  return a.x * b.x + a.y * b.y + a.z * b.z + a.w * b.w;
}

__device__ __forceinline__ u16 f2bf(float x) {  // RNE f32 -> bf16 bits
  union { float f; unsigned u; } v; v.f = x;
  unsigned r = v.u + 0x7fffu + ((v.u >> 16) & 1u);
  return (u16)(r >> 16);
}

// K1: t_bf[4096][96] = bf16(x @ [q_w1; kv_w1]^T) via MFMA. Grid 64.
__global__ __launch_bounds__(256) void k_proj1(const float* __restrict__ x,
                                               const float* __restrict__ qw1,
                                               const float* __restrict__ kvw1,
                                               u16* __restrict__ t_bf) {
  __shared__ __align__(16) u16 Xs[64][72];
  __shared__ __align__(16) u16 Ws[96][72];
  const int r0 = blockIdx.x * 64;
  const int tid = threadIdx.x;
  const int wave = tid >> 6, lane = tid & 63;
  const int lrow = lane & 15, g = lane >> 4;

  f32x4 acc[6];
#pragma unroll
  for (int sub = 0; sub < 6; ++sub) acc[sub] = (f32x4){0.f, 0.f, 0.f, 0.f};

  for (int k0 = 0; k0 < 512; k0 += 64) {
    __syncthreads();
    {  // stage X: 64 rows x 64 k -> bf16
      const int row = tid >> 2, c16 = (tid & 3) * 16;
      const float* __restrict__ src = x + (size_t)(r0 + row) * 512 + k0 + c16;
      u16 tmp[16];
#pragma unroll
      for (int q = 0; q < 4; ++q) {
        const float4 v = *(const float4*)(src + q * 4);
        tmp[q * 4 + 0] = f2bf(v.x); tmp[q * 4 + 1] = f2bf(v.y);
        tmp[q * 4 + 2] = f2bf(v.z); tmp[q * 4 + 3] = f2bf(v.w);
      }
      *(uint4*)&Xs[row][c16] = *(const uint4*)&tmp[0];
      *(uint4*)&Xs[row][c16 + 8] = *(const uint4*)&tmp[8];
    }
    for (int u = tid; u < 384; u += 256) {  // stage W: 96 cols x 64 k
      const int c = u >> 2, c16 = (u & 3) * 16;
      const float* __restrict__ src =
          (c < 32 ? qw1 + (size_t)c * 512 : kvw1 + (size_t)(c - 32) * 512) + k0 + c16;
      u16 tmp[16];
#pragma unroll
      for (int q = 0; q < 4; ++q) {
        const float4 v = *(const float4*)(src + q * 4);
        tmp[q * 4 + 0] = f2bf(v.x); tmp[q * 4 + 1] = f2bf(v.y);
        tmp[q * 4 + 2] = f2bf(v.z); tmp[q * 4 + 3] = f2bf(v.w);
      }
      *(uint4*)&Ws[c][c16] = *(const uint4*)&tmp[0];
      *(uint4*)&Ws[c][c16 + 8] = *(const uint4*)&tmp[8];
    }
    __syncthreads();
    const bf16x8 a0 = *(const bf16x8*)&Xs[wave * 16 + lrow][g * 8];
    const bf16x8 a1 = *(const bf16x8*)&Xs[wave * 16 + lrow][32 + g * 8];
#pragma unroll
    for (int sub = 0; sub < 6; ++sub) {
      const bf16x8 b0 = *(const bf16x8*)&Ws[sub * 16 + lrow][g * 8];
      const bf16x8 b1 = *(const bf16x8*)&Ws[sub * 16 + lrow][32 + g * 8];
      acc[sub] = __builtin_amdgcn_mfma_f32_16x16x32_bf16(a0, b0, acc[sub], 0, 0, 0);
      acc[sub] = __builtin_amdgcn_mfma_f32_16x16x32_bf16(a1, b1, acc[sub], 0, 0, 0);
    }
  }
  // D[x-row = g*4+j][w-col = lrow]
#pragma unroll
  for (int sub = 0; sub < 6; ++sub)
#pragma unroll
    for (int j = 0; j < 4; ++j)
      t_bf[(size_t)(r0 + wave * 16 + g * 4 + j) * 96 + sub * 16 + lrow] = f2bf(acc[sub][j]);
}

// K1b: blocks 0..1: bias2 = dw_b@pw_w^T + pw_b; blocks 2..65: pwbf = bf16(pw_w*dw_w).
__global__ __launch_bounds__(256) void k_tred(const float* __restrict__ pww,
                                              const float* __restrict__ dww,
                                              const float* __restrict__ dwb,
                                              const float* __restrict__ pwb,
                                              float* __restrict__ bias2,
                                              u16* __restrict__ pwbf) {
  const int b = blockIdx.x;
  if (b < 2) {
    const int c = b * 256 + threadIdx.x;
    float acc = 0.f;
    for (int e = 0; e < 512; e += 4)
      acc += dot4(*(const float4*)&pww[(size_t)c * 512 + e], *(const float4*)&dwb[e]);
    bias2[c] = acc + pwb[c];
  } else {
    const int base = (b - 2) * 4096 + threadIdx.x * 16;
    const int e0 = base & 511;
    u16 o[16];
#pragma unroll
    for (int q = 0; q < 4; ++q) {
      const float4 w = *(const float4*)&pww[base + q * 4];
      const float4 d = *(const float4*)&dww[e0 + q * 4];
      o[q * 4 + 0] = f2bf(w.x * d.x); o[q * 4 + 1] = f2bf(w.y * d.y);
      o[q * 4 + 2] = f2bf(w.z * d.z); o[q * 4 + 3] = f2bf(w.w * d.w);
    }
    *(uint4*)&pwbf[base] = *(const uint4*)&o[0];
    *(uint4*)&pwbf[base + 8] = *(const uint4*)&o[8];
  }
}

// K2: q/k/v projections via MFMA. Grid 768 = 64 row-blocks x 12 col-blocks.
// cb<4: q cols (K=32, zero-padded to 64); cb 4..7: k; cb 8..11: v.
__global__ __launch_bounds__(256) void k_proj2(const u16* __restrict__ t_bf,
                                               const float* __restrict__ qw2,
                                               const float* __restrict__ kvw2,
                                               u16* __restrict__ qb,
                                               u16* __restrict__ kb,
                                               float* __restrict__ vh) {
  __shared__ __align__(16) u16 Ts[64][72];
  __shared__ __align__(16) u16 Wsh[128][72];
  const int cb = blockIdx.x % 12;
  const int r0 = (blockIdx.x / 12) * 64;
  const int tid = threadIdx.x;
  const int wave = tid >> 6, lane = tid & 63;
  const int lrow = lane & 15, g = lane >> 4;
  const bool isq = cb < 4;
  const int c0 = isq ? cb * 128 : 512 + (cb - 4) * 128;

  for (int u = tid; u < 512; u += 256) {  // stage T slice (64 x 64, bf16 copy)
    const int row = u >> 3, ch = (u & 7) * 8;
    uint4 v = {0u, 0u, 0u, 0u};
    if (isq) {
      if (ch < 32) v = *(const uint4*)&t_bf[(size_t)(r0 + row) * 96 + ch];
    } else {
      v = *(const uint4*)&t_bf[(size_t)(r0 + row) * 96 + 32 + ch];
    }
    *(uint4*)&Ts[row][ch] = v;
  }
  if (isq) {
    for (int u = tid; u < 1024; u += 256) {  // 128 cols x 32 k
      const int col = u >> 3, cf = (u & 7) * 4;
      const float4 v = *(const float4*)&qw2[(size_t)(c0 + col) * 32 + cf];
      u16 tmp[4] = {f2bf(v.x), f2bf(v.y), f2bf(v.z), f2bf(v.w)};
      *(uint2*)&Wsh[col][cf] = *(const uint2*)&tmp[0];
    }
    for (int u = tid; u < 512; u += 256) {  // zero pad k 32..63
      const int col = u >> 2, ch = 32 + (u & 3) * 8;
      const uint4 z = {0u, 0u, 0u, 0u};
      *(uint4*)&Wsh[col][ch] = z;
    }
  } else {
    for (int u = tid; u < 2048; u += 256) {  // 128 cols x 64 k
      const int col = u >> 4, cf = (u & 15) * 4;
      const float4 v = *(const float4*)&kvw2[(size_t)(c0 - 512 + col) * 64 + cf];
      u16 tmp[4] = {f2bf(v.x), f2bf(v.y), f2bf(v.z), f2bf(v.w)};
      *(uint2*)&Wsh[col][cf] = *(const uint2*)&tmp[0];
    }
  }
  __syncthreads();

  const bf16x8 a0 = *(const bf16x8*)&Ts[wave * 16 + lrow][g * 8];
  const bf16x8 a1 = *(const bf16x8*)&Ts[wave * 16 + lrow][32 + g * 8];
#pragma unroll
  for (int sub = 0; sub < 8; ++sub) {
    const bf16x8 b0 = *(const bf16x8*)&Wsh[sub * 16 + lrow][g * 8];
    const bf16x8 b1 = *(const bf16x8*)&Wsh[sub * 16 + lrow][32 + g * 8];
    f32x4 acc = {0.f, 0.f, 0.f, 0.f};
    acc = __builtin_amdgcn_mfma_f32_16x16x32_bf16(a0, b0, acc, 0, 0, 0);
    acc = __builtin_amdgcn_mfma_f32_16x16x32_bf16(a1, b1, acc, 0, 0, 0);
    const int colg = c0 + sub * 16 + lrow;  // D[t-row g*4+j][w-col lrow]
#pragma unroll
    for (int j = 0; j < 4; ++j) {
      const int n = r0 + wave * 16 + g * 4 + j;
      if (colg < 512) {
        qb[((size_t)(colg >> 6) * NFULL + n) * 64 + (colg & 63)] = f2bf(acc[j] * QSCALE);
      } else if (colg < 1024) {
        const int c2 = colg - 512;
        kb[((size_t)(c2 >> 6) * NFULL + n) * 64 + (c2 & 63)] = f2bf(acc[j]);
      } else {
        const int c2 = colg - 1024;
        vh[((size_t)(c2 >> 6) * NFULL + n) * 64 + (c2 & 63)] = acc[j];
      }
    }
  }
}

// K3: attention. Block (h, qb2, s): 128 queries (q0=qb2*128), keys [s*1024,+1024).
// Each wave: all 8 Q-subtiles in regs, own disjoint 256-key quarter -> K read
// once per block. Partial denom -> dsp[s][h][n]; diag block writes unnormalized
// PV numerator (f32) to wv. Grid 1024 = 8h x 32qb2 x 4s.
__global__ __launch_bounds__(256) void k_attn(const u16* __restrict__ qb,
                                              const u16* __restrict__ kb,
                                              const float* __restrict__ vh,
                                              float* __restrict__ wv,
                                              float* __restrict__ dsp) {
  __shared__ __align__(16) u16 Qs[128][72];
  __shared__ float P_lds[8][16][17];
  __shared__ float Ds[4][8][16];

  const int h = blockIdx.x & 7;
  const int qb2 = (blockIdx.x >> 3) & 31;
  const int s = blockIdx.x >> 8;
  const int q0 = qb2 * 128;
  const int tid = threadIdx.x;
  const int wave = tid >> 6, lane = tid & 63;
  const int lrow = lane & 15, g = lane >> 4;

  // stage Q (128 rows x 64 bf16) once
  for (int u = tid; u < 1024; u += 256) {
    const int row = u >> 3, ch = (u & 7) * 8;
    *(uint4*)&Qs[row][ch] =
        *(const uint4*)&qb[((size_t)h * NFULL + q0 + row) * 64 + ch];
  }
  __syncthreads();

  bf16x8 qf[8][2];
#pragma unroll
  for (int j = 0; j < 8; ++j) {
    qf[j][0] = *(const bf16x8*)&Qs[j * 16 + lrow][g * 8];
    qf[j][1] = *(const bf16x8*)&Qs[j * 16 + lrow][32 + g * 8];
  }

  const bool hasdiag = (s == (q0 >> 10));
  int dj[8];
#pragma unroll
  for (int j = 0; j < 8; ++j) {
    const int gj = (q0 >> 4) + j - s * 64;  // local key-group of sub j's diag
    dj[j] = (hasdiag && ((gj >> 4) == wave)) ? (gj & 15) : -1;
  }

  float dsum[8];
#pragma unroll
  for (int j = 0; j < 8; ++j) dsum[j] = 0.f;

  const u16* __restrict__ Kp =
      kb + (size_t)h * NFULL * 64 + ((size_t)(s * 1024 + wave * 256) + lrow) * 64 + g * 8;

  auto process = [&](bf16x8 k0, bf16x8 k1, int ktg) {
    f32x4 a[8];
    __builtin_amdgcn_s_setprio(1);
#pragma unroll
    for (int j = 0; j < 8; ++j) {
      f32x4 t4 = {0.f, 0.f, 0.f, 0.f};
      t4 = __builtin_amdgcn_mfma_f32_16x16x32_bf16(k0, qf[j][0], t4, 0, 0, 0);
      t4 = __builtin_amdgcn_mfma_f32_16x16x32_bf16(k1, qf[j][1], t4, 0, 0, 0);
      a[j] = t4;
    }
    __builtin_amdgcn_s_setprio(0);
#pragma unroll
    for (int j = 0; j < 8; ++j) {
      const float e0 = EXP2(a[j][0]);
      const float e1 = EXP2(a[j][1]);
      const float e2 = EXP2(a[j][2]);
      const float e3 = EXP2(a[j][3]);
      dsum[j] += (e0 + e1) + (e2 + e3);
      if (ktg == dj[j]) {  // diag 16x16 of q-sub j: D[key g*4+i][query lrow]
        const int rr = g * 4;
        P_lds[j][rr + 0][lrow] = (rr + 0 <= lrow) ? e0 : 0.f;
        P_lds[j][rr + 1][lrow] = (rr + 1 <= lrow) ? e1 : 0.f;
        P_lds[j][rr + 2][lrow] = (rr + 2 <= lrow) ? e2 : 0.f;
        P_lds[j][rr + 3][lrow] = (rr + 3 <= lrow) ? e3 : 0.f;
      }
    }
  };

  // 16 key-groups per wave, depth-2 rolling register prefetch
  bf16x8 k0a = *(const bf16x8*)(Kp);
  bf16x8 k0b = *(const bf16x8*)(Kp + 32);
  bf16x8 k1a = *(const bf16x8*)(Kp + 1024);
  bf16x8 k1b = *(const bf16x8*)(Kp + 1024 + 32);
  for (int kt = 0; kt < 14; kt += 2) {
    process(k0a, k0b, kt);
    k0a = *(const bf16x8*)(Kp + (size_t)(kt + 2) * 1024);
    k0b = *(const bf16x8*)(Kp + (size_t)(kt + 2) * 1024 + 32);
    process(k1a, k1b, kt + 1);
    k1a = *(const bf16x8*)(Kp + (size_t)(kt + 3) * 1024);
    k1b = *(const bf16x8*)(Kp + (size_t)(kt + 3) * 1024 + 32);
  }
  process(k0a, k0b, 14);
  process(k1a, k1b, 15);

#pragma unroll
  for (int j = 0; j < 8; ++j) {  // reduce over key-row groups (g)
    dsum[j] += __shfl_xor(dsum[j], 16);
    dsum[j] += __shfl_xor(dsum[j], 32);
  }
  if (g == 0) {
#pragma unroll
    for (int j = 0; j < 8; ++j) Ds[wave][j][lrow] = dsum[j];
  }
  __syncthreads();

  if (tid < 128) {  // block-level partial denominator for this s-quarter
    const int j = tid >> 4, r = tid & 15;
    const float den = Ds[0][j][r] + Ds[1][j][r] + Ds[2][j][r] + Ds[3][j][r];
    dsp[((size_t)s * HEADS + h) * NFULL + q0 + j * 16 + r] = den;
  }

  if (hasdiag) {  // PV numerator (unnormalized); wave handles subs 2w, 2w+1
#pragma unroll
    for (int t = 0; t < 2; ++t) {
      const int sub = wave * 2 + t;
      const float* __restrict__ V =
          vh + ((size_t)h * NFULL + q0 + sub * 16) * 64 + g * 16;
      float o[16];
#pragma unroll
      for (int dd = 0; dd < 16; ++dd) o[dd] = 0.f;
#pragma unroll
      for (int k = 0; k < 16; ++k) {
        const float p = P_lds[sub][k][lrow];
        const float4 v0 = *(const float4*)&V[k * 64 + 0];
        const float4 v1 = *(const float4*)&V[k * 64 + 4];
        const float4 v2 = *(const float4*)&V[k * 64 + 8];
        const float4 v3 = *(const float4*)&V[k * 64 + 12];
        o[0] += p * v0.x;  o[1] += p * v0.y;  o[2] += p * v0.z;  o[3] += p * v0.w;
        o[4] += p * v1.x;  o[5] += p * v1.y;  o[6] += p * v1.z;  o[7] += p * v1.w;
        o[8] += p * v2.x;  o[9] += p * v2.y;  o[10] += p * v2.z; o[11] += p * v2.w;
        o[12] += p * v3.x; o[13] += p * v3.y; o[14] += p * v3.z; o[15] += p * v3.w;
      }
      float* __restrict__ op =
          wv + (size_t)(q0 + sub * 16 + lrow) * CDIM + h * 64 + g * 16;
#pragma unroll
      for (int c4 = 0; c4 < 4; ++c4) {
        float4 r;
        r.x = o[c4 * 4 + 0]; r.y = o[c4 * 4 + 1];
        r.z = o[c4 * 4 + 2]; r.w = o[c4 * 4 + 3];
        *(float4*)&op[c4 * 4] = r;
      }
    }
  }
}

// K4: y = normalize(wv) @ pwbf^T + bias2 + x. Normalization folded into the
// bf16 staging convert; denom = sum of 4 dsp splits. Grid 512.
__global__ __launch_bounds__(256) void k_dyn(const float* __restrict__ wv,
                                             const float* __restrict__ x,
                                             const u16* __restrict__ pwbf,
                                             const float* __restrict__ bias2,
                                             const float* __restrict__ dsp,
                                             float* __restrict__ y) {
  __shared__ __align__(16) u16 Ab[64][72];
  __shared__ __align__(16) u16 Wb[64][72];
  const int rb = blockIdx.x >> 3, cb = blockIdx.x & 7;
  const int r0 = rb * 64, c0 = cb * 64;
  const int tid = threadIdx.x;
  const int wave = tid >> 6, lane = tid & 63;
  const int lrow = lane & 15, g = lane >> 4;
  const int srow = tid >> 2;
  const int skc = (tid & 3) * 16;

  float inv8[8];
#pragma unroll
  for (int hh = 0; hh < 8; ++hh) {
    const size_t base = (size_t)hh * NFULL + r0 + srow;
    inv8[hh] = 1.0f / (dsp[base] + dsp[(size_t)8 * NFULL + base] +
                       dsp[(size_t)16 * NFULL + base] + dsp[(size_t)24 * NFULL + base]);
  }

  f32x4 acc[4];
#pragma unroll
  for (int ct = 0; ct < 4; ++ct) acc[ct] = (f32x4){0.f, 0.f, 0.f, 0.f};

  const float* __restrict__ ap = wv + (size_t)(r0 + srow) * 512 + skc;
  const u16* __restrict__ wp = pwbf + (size_t)(c0 + srow) * 512 + skc;
  float4 a4[4];
#pragma unroll
  for (int e = 0; e < 4; ++e) a4[e] = *(const float4*)(ap + e * 4);
  uint4 w0 = *(const uint4*)wp;
  uint4 w1 = *(const uint4*)(wp + 8);

  for (int k0 = 0; k0 < 512; k0 += 64) {
    const float sc = inv8[k0 >> 6];
    u16 ab16[16];
#pragma unroll
    for (int e = 0; e < 4; ++e) {
      ab16[e * 4 + 0] = f2bf(a4[e].x * sc);
      ab16[e * 4 + 1] = f2bf(a4[e].y * sc);
      ab16[e * 4 + 2] = f2bf(a4[e].z * sc);
      ab16[e * 4 + 3] = f2bf(a4[e].w * sc);
    }
    __syncthreads();
    *(uint4*)&Ab[srow][skc] = *(const uint4*)&ab16[0];
    *(uint4*)&Ab[srow][skc + 8] = *(const uint4*)&ab16[8];
    *(uint4*)&Wb[srow][skc] = w0;
    *(uint4*)&Wb[srow][skc + 8] = w1;
    __syncthreads();
    if (k0 + 64 < 512) {
#pragma unroll
      for (int e = 0; e < 4; ++e) a4[e] = *(const float4*)(ap + k0 + 64 + e * 4);
      w0 = *(const uint4*)(wp + k0 + 64);
      w1 = *(const uint4*)(wp + k0 + 64 + 8);
    }
#pragma unroll
    for (int kk = 0; kk < 2; ++kk) {
      const bf16x8 af = *(const bf16x8*)&Ab[wave * 16 + lrow][kk * 32 + g * 8];
#pragma unroll
      for (int ct = 0; ct < 4; ++ct) {
        const bf16x8 wf = *(const bf16x8*)&Wb[ct * 16 + lrow][kk * 32 + g * 8];
        acc[ct] = __builtin_amdgcn_mfma_f32_16x16x32_bf16(wf, af, acc[ct], 0, 0, 0);
      }
    }
  }
  const int row = r0 + wave * 16 + lrow;
#pragma unroll
  for (int ct = 0; ct < 4; ++ct) {
    const int c = c0 + ct * 16 + g * 4;
    const float4 bb = *(const float4*)&bias2[c];
    const float4 xv = *(const float4*)&x[(size_t)row * 512 + c];
    float4 res;
    res.x = acc[ct][0] + bb.x + xv.x;
    res.y = acc[ct][1] + bb.y + xv.y;
    res.z = acc[ct][2] + bb.z + xv.z;
    res.w = acc[ct][3] + bb.w + xv.w;
    *(float4*)&y[(size_t)row * 512 + c] = res;
  }
}

// K5: out = ((y @ p_w1^T) @ p_w2^T) fused via MFMA. Grid 256.
__global__ __launch_bounds__(256) void k_pout(const float* __restrict__ y,
                                              const float* __restrict__ pw1,
                                              const float* __restrict__ pw2,
                                              float* __restrict__ out) {
  __shared__ __align__(16) u16 yb[16][520];
  __shared__ float tp_part[2][32][17];
  const int r0 = blockIdx.x * 16;
  const int tid = threadIdx.x;
  const int wave = tid >> 6, lane = tid & 63;
  const int lrow = lane & 15, g = lane >> 4;

  for (int rep = 0; rep < 8; ++rep) {
    const int l = rep * 256 + tid;
    const int row = l >> 7, c4 = (l & 127) << 2;
    const float4 v = *(const float4*)&y[(size_t)(r0 + row) * 512 + c4];
    yb[row][c4 + 0] = f2bf(v.x); yb[row][c4 + 1] = f2bf(v.y);
    yb[row][c4 + 2] = f2bf(v.z); yb[row][c4 + 3] = f2bf(v.w);
  }
  __syncthreads();

  {
    const int ct1 = wave & 1, kh = wave >> 1;
    f32x4 acc = {0.f, 0.f, 0.f, 0.f};
#pragma unroll
    for (int ks = 0; ks < 8; ++ks) {
      const int K = kh * 256 + ks * 32 + g * 8;
      union { u16 a[8]; bf16x8 v; } aw;
      const float4 wv0 = *(const float4*)&pw1[(size_t)(ct1 * 16 + lrow) * 512 + K];
      const float4 wv1 = *(const float4*)&pw1[(size_t)(ct1 * 16 + lrow) * 512 + K + 4];
      aw.a[0] = f2bf(wv0.x); aw.a[1] = f2bf(wv0.y);
      aw.a[2] = f2bf(wv0.z); aw.a[3] = f2bf(wv0.w);
      aw.a[4] = f2bf(wv1.x); aw.a[5] = f2bf(wv1.y);
      aw.a[6] = f2bf(wv1.z); aw.a[7] = f2bf(wv1.w);
      const bf16x8 bf = *(const bf16x8*)&yb[lrow][K];
      acc = __builtin_amdgcn_mfma_f32_16x16x32_bf16(aw.v, bf, acc, 0, 0, 0);
    }
#pragma unroll
    for (int j = 0; j < 4; ++j)
      tp_part[kh][ct1 * 16 + g * 4 + j][lrow] = acc[j];
  }
  __syncthreads();

  union { u16 a[8]; bf16x8 v; } bq;
#pragma unroll
  for (int i = 0; i < 8; ++i) {
    const int k = g * 8 + i;
    bq.a[i] = f2bf(tp_part[0][k][lrow] + tp_part[1][k][lrow]);
  }

#pragma unroll
  for (int t = 0; t < 8; ++t) {
    const int ct = wave * 8 + t;
    union { u16 a[8]; bf16x8 v; } aw;
    const float4 wv0 = *(const float4*)&pw2[(size_t)(ct * 16 + lrow) * 32 + g * 8];
    const float4 wv1 = *(const float4*)&pw2[(size_t)(ct * 16 + lrow) * 32 + g * 8 + 4];
    aw.a[0] = f2bf(wv0.x); aw.a[1] = f2bf(wv0.y);
    aw.a[2] = f2bf(wv0.z); aw.a[3] = f2bf(wv0.w);
    aw.a[4] = f2bf(wv1.x); aw.a[5] = f2bf(wv1.y);
    aw.a[6] = f2bf(wv1.z); aw.a[7] = f2bf(wv1.w);
    f32x4 acc = {0.f, 0.f, 0.f, 0.f};
    acc = __builtin_amdgcn_mfma_f32_16x16x32_bf16(aw.v, bq.v, acc, 0, 0, 0);
    float4 res;
    res.x = acc[0]; res.y = acc[1]; res.z = acc[2]; res.w = acc[3];
    *(float4*)&out[(size_t)(r0 + lrow) * 512 + ct * 16 + g * 4] = res;
  }
}

extern "C" void kernel_launch(void* const* d_in, const int* in_sizes, int n_in,
                              void* d_out, int out_size, void* d_ws, size_t ws_size,
                              hipStream_t stream) {
  const float* x     = (const float*)d_in[0];
  const float* q_w1  = (const float*)d_in[1];
  const float* q_w2  = (const float*)d_in[2];
  const float* kv_w1 = (const float*)d_in[3];
  const float* kv_w2 = (const float*)d_in[4];
  const float* dw_w  = (const float*)d_in[5];
  const float* dw_b  = (const float*)d_in[6];
  const float* pw_w  = (const float*)d_in[7];
  const float* pw_b  = (const float*)d_in[8];
  const float* p_w1  = (const float*)d_in[9];
  const float* p_w2  = (const float*)d_in[10];
  float* out = (float*)d_out;

  char* ws = (char*)d_ws;
  u16*   t_bf  = (u16*)ws;                               // 4096*96 u16 (786KB)
  float* dsp   = (float*)ws;                             // alias: 4*8*4096 f32 (dead t_bf)
  float* bias2 = (float*)(ws + 786432);                  // 1024 f32
  u16*   pwbf  = (u16*)(ws + 786432 + 4096);             // 512*512 u16 (512KB)
  u16*   qbw   = pwbf + 262144;                          // 2M u16 (4MB)
  u16*   kbw   = qbw + (size_t)HEADS * NFULL * DDIM;     // 2M u16 (4MB)
  float* y     = (float*)qbw;                            // alias over qbw+kbw (8MB)
  float* vh    = (float*)(kbw + (size_t)HEADS * NFULL * DDIM);  // 2M f32 (8MB)
  float* wvf   = vh + (size_t)HEADS * NFULL * DDIM;      // 2M f32 (8MB)

  k_proj1<<<NFULL / 64, 256, 0, stream>>>(x, q_w1, kv_w1, t_bf);
  k_tred<<<66, 256, 0, stream>>>(pw_w, dw_w, dw_b, pw_b, bias2, pwbf);
  k_proj2<<<(NFULL / 64) * 12, 256, 0, stream>>>(t_bf, q_w2, kv_w2, qbw, kbw, vh);
  k_attn<<<4 * HEADS * (NFULL / 128), 256, 0, stream>>>(qbw, kbw, vh, wvf, dsp);
  k_dyn<<<(NFULL / 64) * 8, 256, 0, stream>>>(wvf, x, pwbf, bias2, dsp, y);
  k_pout<<<NFULL / 16, 256, 0, stream>>>(y, p_w1, p_w2, out);
}

// Round 8
// 118.102 us; speedup vs baseline: 1.1770x; 1.1770x over previous
//
#include <hip/hip_runtime.h>

#define NFULL 4096
#define CDIM  512
#define HEADS 8
#define DDIM  64

typedef unsigned short u16;
typedef short bf16x8 __attribute__((ext_vector_type(8)));
typedef float f32x4 __attribute__((ext_vector_type(4)));

#define EXP2(x) exp2f(x)

// q pre-scaled by SCALE * log2(e) so exp(s) == exp2(s').
#define QSCALE 11.541560327111707f  // 8 * 1.4426950408889634

__device__ __forceinline__ float dot4(float4 a, float4 b) {
  return a.x * b.x + a.y * b.y + a.z * b.z + a.w * b.w;
}

__device__ __forceinline__ u16 f2bf(float x) {  // RNE f32 -> bf16 bits
  union { float f; unsigned u; } v; v.f = x;
  unsigned r = v.u + 0x7fffu + ((v.u >> 16) & 1u);
  return (u16)(r >> 16);
}

// K1: t_bf[4096][96] = bf16(x @ [q_w1; kv_w1]^T) via MFMA. Grid 64.
__global__ __launch_bounds__(256) void k_proj1(const float* __restrict__ x,
                                               const float* __restrict__ qw1,
                                               const float* __restrict__ kvw1,
                                               u16* __restrict__ t_bf) {
  __shared__ __align__(16) u16 Xs[64][72];
  __shared__ __align__(16) u16 Ws[96][72];
  const int r0 = blockIdx.x * 64;
  const int tid = threadIdx.x;
  const int wave = tid >> 6, lane = tid & 63;
  const int lrow = lane & 15, g = lane >> 4;

  f32x4 acc[6];
#pragma unroll
  for (int sub = 0; sub < 6; ++sub) acc[sub] = (f32x4){0.f, 0.f, 0.f, 0.f};

  for (int k0 = 0; k0 < 512; k0 += 64) {
    __syncthreads();
    {  // stage X: 64 rows x 64 k -> bf16
      const int row = tid >> 2, c16 = (tid & 3) * 16;
      const float* __restrict__ src = x + (size_t)(r0 + row) * 512 + k0 + c16;
      u16 tmp[16];
#pragma unroll
      for (int q = 0; q < 4; ++q) {
        const float4 v = *(const float4*)(src + q * 4);
        tmp[q * 4 + 0] = f2bf(v.x); tmp[q * 4 + 1] = f2bf(v.y);
        tmp[q * 4 + 2] = f2bf(v.z); tmp[q * 4 + 3] = f2bf(v.w);
      }
      *(uint4*)&Xs[row][c16] = *(const uint4*)&tmp[0];
      *(uint4*)&Xs[row][c16 + 8] = *(const uint4*)&tmp[8];
    }
    for (int u = tid; u < 384; u += 256) {  // stage W: 96 cols x 64 k
      const int c = u >> 2, c16 = (u & 3) * 16;
      const float* __restrict__ src =
          (c < 32 ? qw1 + (size_t)c * 512 : kvw1 + (size_t)(c - 32) * 512) + k0 + c16;
      u16 tmp[16];
#pragma unroll
      for (int q = 0; q < 4; ++q) {
        const float4 v = *(const float4*)(src + q * 4);
        tmp[q * 4 + 0] = f2bf(v.x); tmp[q * 4 + 1] = f2bf(v.y);
        tmp[q * 4 + 2] = f2bf(v.z); tmp[q * 4 + 3] = f2bf(v.w);
      }
      *(uint4*)&Ws[c][c16] = *(const uint4*)&tmp[0];
      *(uint4*)&Ws[c][c16 + 8] = *(const uint4*)&tmp[8];
    }
    __syncthreads();
    const bf16x8 a0 = *(const bf16x8*)&Xs[wave * 16 + lrow][g * 8];
    const bf16x8 a1 = *(const bf16x8*)&Xs[wave * 16 + lrow][32 + g * 8];
#pragma unroll
    for (int sub = 0; sub < 6; ++sub) {
      const bf16x8 b0 = *(const bf16x8*)&Ws[sub * 16 + lrow][g * 8];
      const bf16x8 b1 = *(const bf16x8*)&Ws[sub * 16 + lrow][32 + g * 8];
      acc[sub] = __builtin_amdgcn_mfma_f32_16x16x32_bf16(a0, b0, acc[sub], 0, 0, 0);
      acc[sub] = __builtin_amdgcn_mfma_f32_16x16x32_bf16(a1, b1, acc[sub], 0, 0, 0);
    }
  }
#pragma unroll
  for (int sub = 0; sub < 6; ++sub)
#pragma unroll
    for (int j = 0; j < 4; ++j)
      t_bf[(size_t)(r0 + wave * 16 + g * 4 + j) * 96 + sub * 16 + lrow] = f2bf(acc[sub][j]);
}

// K1b: blocks 0..1: bias2 = dw_b@pw_w^T + pw_b; blocks 2..65: pwbf = bf16(pw_w*dw_w).
__global__ __launch_bounds__(256) void k_tred(const float* __restrict__ pww,
                                              const float* __restrict__ dww,
                                              const float* __restrict__ dwb,
                                              const float* __restrict__ pwb,
                                              float* __restrict__ bias2,
                                              u16* __restrict__ pwbf) {
  const int b = blockIdx.x;
  if (b < 2) {
    const int c = b * 256 + threadIdx.x;
    float acc = 0.f;
    for (int e = 0; e < 512; e += 4)
      acc += dot4(*(const float4*)&pww[(size_t)c * 512 + e], *(const float4*)&dwb[e]);
    bias2[c] = acc + pwb[c];
  } else {
    const int base = (b - 2) * 4096 + threadIdx.x * 16;
    const int e0 = base & 511;
    u16 o[16];
#pragma unroll
    for (int q = 0; q < 4; ++q) {
      const float4 w = *(const float4*)&pww[base + q * 4];
      const float4 d = *(const float4*)&dww[e0 + q * 4];
      o[q * 4 + 0] = f2bf(w.x * d.x); o[q * 4 + 1] = f2bf(w.y * d.y);
      o[q * 4 + 2] = f2bf(w.z * d.z); o[q * 4 + 3] = f2bf(w.w * d.w);
    }
    *(uint4*)&pwbf[base] = *(const uint4*)&o[0];
    *(uint4*)&pwbf[base + 8] = *(const uint4*)&o[8];
  }
}

// K2: q/k/v projections via MFMA. Grid 768 = 64 row-blocks x 12 col-blocks.
__global__ __launch_bounds__(256) void k_proj2(const u16* __restrict__ t_bf,
                                               const float* __restrict__ qw2,
                                               const float* __restrict__ kvw2,
                                               u16* __restrict__ qb,
                                               u16* __restrict__ kb,
                                               float* __restrict__ vh) {
  __shared__ __align__(16) u16 Ts[64][72];
  __shared__ __align__(16) u16 Wsh[128][72];
  const int cb = blockIdx.x % 12;
  const int r0 = (blockIdx.x / 12) * 64;
  const int tid = threadIdx.x;
  const int wave = tid >> 6, lane = tid & 63;
  const int lrow = lane & 15, g = lane >> 4;
  const bool isq = cb < 4;
  const int c0 = isq ? cb * 128 : 512 + (cb - 4) * 128;

  for (int u = tid; u < 512; u += 256) {
    const int row = u >> 3, ch = (u & 7) * 8;
    uint4 v = {0u, 0u, 0u, 0u};
    if (isq) {
      if (ch < 32) v = *(const uint4*)&t_bf[(size_t)(r0 + row) * 96 + ch];
    } else {
      v = *(const uint4*)&t_bf[(size_t)(r0 + row) * 96 + 32 + ch];
    }
    *(uint4*)&Ts[row][ch] = v;
  }
  if (isq) {
    for (int u = tid; u < 1024; u += 256) {
      const int col = u >> 3, cf = (u & 7) * 4;
      const float4 v = *(const float4*)&qw2[(size_t)(c0 + col) * 32 + cf];
      u16 tmp[4] = {f2bf(v.x), f2bf(v.y), f2bf(v.z), f2bf(v.w)};
      *(uint2*)&Wsh[col][cf] = *(const uint2*)&tmp[0];
    }
    for (int u = tid; u < 512; u += 256) {
      const int col = u >> 2, ch = 32 + (u & 3) * 8;
      const uint4 z = {0u, 0u, 0u, 0u};
      *(uint4*)&Wsh[col][ch] = z;
    }
  } else {
    for (int u = tid; u < 2048; u += 256) {
      const int col = u >> 4, cf = (u & 15) * 4;
      const float4 v = *(const float4*)&kvw2[(size_t)(c0 - 512 + col) * 64 + cf];
      u16 tmp[4] = {f2bf(v.x), f2bf(v.y), f2bf(v.z), f2bf(v.w)};
      *(uint2*)&Wsh[col][cf] = *(const uint2*)&tmp[0];
    }
  }
  __syncthreads();

  const bf16x8 a0 = *(const bf16x8*)&Ts[wave * 16 + lrow][g * 8];
  const bf16x8 a1 = *(const bf16x8*)&Ts[wave * 16 + lrow][32 + g * 8];
#pragma unroll
  for (int sub = 0; sub < 8; ++sub) {
    const bf16x8 b0 = *(const bf16x8*)&Wsh[sub * 16 + lrow][g * 8];
    const bf16x8 b1 = *(const bf16x8*)&Wsh[sub * 16 + lrow][32 + g * 8];
    f32x4 acc = {0.f, 0.f, 0.f, 0.f};
    acc = __builtin_amdgcn_mfma_f32_16x16x32_bf16(a0, b0, acc, 0, 0, 0);
    acc = __builtin_amdgcn_mfma_f32_16x16x32_bf16(a1, b1, acc, 0, 0, 0);
    const int colg = c0 + sub * 16 + lrow;
#pragma unroll
    for (int j = 0; j < 4; ++j) {
      const int n = r0 + wave * 16 + g * 4 + j;
      if (colg < 512) {
        qb[((size_t)(colg >> 6) * NFULL + n) * 64 + (colg & 63)] = f2bf(acc[j] * QSCALE);
      } else if (colg < 1024) {
        const int c2 = colg - 512;
        kb[((size_t)(c2 >> 6) * NFULL + n) * 64 + (c2 & 63)] = f2bf(acc[j]);
      } else {
        const int c2 = colg - 1024;
        vh[((size_t)(c2 >> 6) * NFULL + n) * 64 + (c2 & 63)] = acc[j];
      }
    }
  }
}

// K3: attention. Block (h, qt, s): 64 queries, keys [s*2048,+2048) in 32 tiles
// of 64 keys. Each wave owns rows w*16..+16 of every tile: stages them itself
// via global_load_lds into a 4-deep circular swizzled LDS buffer (counted
// vmcnt, no barriers in the main loop) and MFMAs them vs its 4 Q-subtiles.
// Partial denom -> dsp[s][h][n]; diag block writes unnormalized PV to wv.
__global__ __launch_bounds__(256, 4) void k_attn(const u16* __restrict__ qb,
                                                 const u16* __restrict__ kb,
                                                 const float* __restrict__ vh,
                                                 float* __restrict__ wv,
                                                 float* __restrict__ dsp) {
  __shared__ __align__(16) u16 KB[4][64][64];  // 32 KB, rows XOR-swizzled
  __shared__ float P_lds[4][16][17];
  __shared__ float Ds[4][4][16];

  const int h = blockIdx.x & 7;            // XCD affinity: head == XCD
  const int qt = (blockIdx.x >> 3) & 63;
  const int s = blockIdx.x >> 9;
  const int q0 = qt * 64;
  const int tid = threadIdx.x;
  const int wave = tid >> 6, lane = tid & 63;
  const int lrow = lane & 15, g = lane >> 4;

  const u16* __restrict__ Qg = qb + ((size_t)h * NFULL + q0) * 64;
  const u16* __restrict__ Kg = kb + ((size_t)h * NFULL + (size_t)s * 2048) * 64;

  bf16x8 qf[4][2];
#pragma unroll
  for (int f = 0; f < 4; ++f) {
    qf[f][0] = *(const bf16x8*)&Qg[(f * 16 + lrow) * 64 + g * 8];
    qf[f][1] = *(const bf16x8*)&Qg[(f * 16 + lrow) * 64 + 32 + g * 8];
  }

  // staging lane geometry: lane stages 16B of row (wave*16 + c*8 + lane>>3),
  // source column chunk pre-swizzled so linear LDS dest == swizzled layout.
  const int srow8 = lane >> 3;                  // row&7 for both c (c*8 = 0 mod 8)
  const int scol = ((lane & 7) ^ srow8) << 3;   // u16 units (16B chunk)

#define STAGE(T, B)                                                           \
  do {                                                                        \
    const u16* tb_ = Kg + (size_t)(T) * 64 * 64;                              \
    {                                                                         \
      const u16* src_ = tb_ + (wave * 16 + srow8) * 64 + scol;                \
      u16* dst_ = &KB[(B)][wave * 16][0];                                     \
      __builtin_amdgcn_global_load_lds(                                       \
          (const __attribute__((address_space(1))) unsigned*)src_,            \
          (__attribute__((address_space(3))) unsigned*)dst_, 16, 0, 0);       \
    }                                                                         \
    {                                                                         \
      const u16* src_ = tb_ + (wave * 16 + 8 + srow8) * 64 + scol;            \
      u16* dst_ = &KB[(B)][wave * 16][0] + 512;                               \
      __builtin_amdgcn_global_load_lds(                                       \
          (const __attribute__((address_space(1))) unsigned*)src_,            \
          (__attribute__((address_space(3))) unsigned*)dst_, 16, 0, 0);       \
    }                                                                         \
  } while (0)

  const int rsw = wave * 16 + lrow;            // this lane's MFMA key row
  const int x0 = (g ^ (lrow & 7)) * 8;         // swizzled read cols (u16)
  const int x1 = ((g + 4) ^ (lrow & 7)) * 8;

  float dsum[4] = {0.f, 0.f, 0.f, 0.f};
  const bool dg = (s == (qt >> 5));
  const int tdiag = qt & 31;

  STAGE(0, 0); STAGE(1, 1); STAGE(2, 2);

  for (int t = 0; t < 32; ++t) {
    const int b = t & 3;
    if (t + 3 < 32) STAGE(t + 3, (t + 3) & 3);
    if (t < 29)       asm volatile("s_waitcnt vmcnt(6)" ::: "memory");
    else if (t == 29) asm volatile("s_waitcnt vmcnt(4)" ::: "memory");
    else if (t == 30) asm volatile("s_waitcnt vmcnt(2)" ::: "memory");
    else              asm volatile("s_waitcnt vmcnt(0)" ::: "memory");

    const bf16x8 kf0 = *(const bf16x8*)&KB[b][rsw][x0];
    const bf16x8 kf1 = *(const bf16x8*)&KB[b][rsw][x1];
    f32x4 a[4];
    __builtin_amdgcn_s_setprio(1);
#pragma unroll
    for (int f = 0; f < 4; ++f) {
      f32x4 t4 = {0.f, 0.f, 0.f, 0.f};
      t4 = __builtin_amdgcn_mfma_f32_16x16x32_bf16(kf0, qf[f][0], t4, 0, 0, 0);
      t4 = __builtin_amdgcn_mfma_f32_16x16x32_bf16(kf1, qf[f][1], t4, 0, 0, 0);
      a[f] = t4;
    }
    __builtin_amdgcn_s_setprio(0);
    const bool isd = dg && (t == tdiag);
#pragma unroll
    for (int f = 0; f < 4; ++f) {
      const float e0 = EXP2(a[f][0]);
      const float e1 = EXP2(a[f][1]);
      const float e2 = EXP2(a[f][2]);
      const float e3 = EXP2(a[f][3]);
      dsum[f] += (e0 + e1) + (e2 + e3);
      if (isd && f == wave) {  // wave w owns key-group w == diag of q-sub w
        const int rr = g * 4;
        P_lds[wave][rr + 0][lrow] = (rr + 0 <= lrow) ? e0 : 0.f;
        P_lds[wave][rr + 1][lrow] = (rr + 1 <= lrow) ? e1 : 0.f;
        P_lds[wave][rr + 2][lrow] = (rr + 2 <= lrow) ? e2 : 0.f;
        P_lds[wave][rr + 3][lrow] = (rr + 3 <= lrow) ? e3 : 0.f;
      }
    }
  }
#undef STAGE

#pragma unroll
  for (int f = 0; f < 4; ++f) {  // reduce over key-row groups (g)
    dsum[f] += __shfl_xor(dsum[f], 16);
    dsum[f] += __shfl_xor(dsum[f], 32);
  }
  if (g == 0) {
#pragma unroll
    for (int f = 0; f < 4; ++f) Ds[wave][f][lrow] = dsum[f];
  }
  __syncthreads();

  if (tid < 64) {  // partial denominator over this block's 2048 keys
    const int f = tid >> 4, r = tid & 15;
    const float den = Ds[0][f][r] + Ds[1][f][r] + Ds[2][f][r] + Ds[3][f][r];
    dsp[((size_t)s * HEADS + h) * NFULL + q0 + f * 16 + r] = den;
  }

  if (dg) {  // PV numerator (unnormalized) for q-sub == wave
    const float* __restrict__ V =
        vh + ((size_t)h * NFULL + q0 + wave * 16) * 64 + g * 16;
    float o[16];
#pragma unroll
    for (int dd = 0; dd < 16; ++dd) o[dd] = 0.f;
#pragma unroll
    for (int k = 0; k < 16; ++k) {
      const float p = P_lds[wave][k][lrow];
      const float4 v0 = *(const float4*)&V[k * 64 + 0];
      const float4 v1 = *(const float4*)&V[k * 64 + 4];
      const float4 v2 = *(const float4*)&V[k * 64 + 8];
      const float4 v3 = *(const float4*)&V[k * 64 + 12];
      o[0] += p * v0.x;  o[1] += p * v0.y;  o[2] += p * v0.z;  o[3] += p * v0.w;
      o[4] += p * v1.x;  o[5] += p * v1.y;  o[6] += p * v1.z;  o[7] += p * v1.w;
      o[8] += p * v2.x;  o[9] += p * v2.y;  o[10] += p * v2.z; o[11] += p * v2.w;
      o[12] += p * v3.x; o[13] += p * v3.y; o[14] += p * v3.z; o[15] += p * v3.w;
    }
    float* __restrict__ op =
        wv + (size_t)(q0 + wave * 16 + lrow) * CDIM + h * 64 + g * 16;
#pragma unroll
    for (int c4 = 0; c4 < 4; ++c4) {
      float4 r;
      r.x = o[c4 * 4 + 0]; r.y = o[c4 * 4 + 1];
      r.z = o[c4 * 4 + 2]; r.w = o[c4 * 4 + 3];
      *(float4*)&op[c4 * 4] = r;
    }
  }
}

// K4: y = normalize(wv) @ pwbf^T + bias2 + x; denom = sum of 2 dsp splits.
__global__ __launch_bounds__(256) void k_dyn(const float* __restrict__ wv,
                                             const float* __restrict__ x,
                                             const u16* __restrict__ pwbf,
                                             const float* __restrict__ bias2,
                                             const float* __restrict__ dsp,
                                             float* __restrict__ y) {
  __shared__ __align__(16) u16 Ab[64][72];
  __shared__ __align__(16) u16 Wb[64][72];
  const int rb = blockIdx.x >> 3, cb = blockIdx.x & 7;
  const int r0 = rb * 64, c0 = cb * 64;
  const int tid = threadIdx.x;
  const int wave = tid >> 6, lane = tid & 63;
  const int lrow = lane & 15, g = lane >> 4;
  const int srow = tid >> 2;
  const int skc = (tid & 3) * 16;

  float inv8[8];
#pragma unroll
  for (int hh = 0; hh < 8; ++hh) {
    const size_t base = (size_t)hh * NFULL + r0 + srow;
    inv8[hh] = 1.0f / (dsp[base] + dsp[(size_t)8 * NFULL + base]);
  }

  f32x4 acc[4];
#pragma unroll
  for (int ct = 0; ct < 4; ++ct) acc[ct] = (f32x4){0.f, 0.f, 0.f, 0.f};

  const float* __restrict__ ap = wv + (size_t)(r0 + srow) * 512 + skc;
  const u16* __restrict__ wp = pwbf + (size_t)(c0 + srow) * 512 + skc;
  float4 a4[4];
#pragma unroll
  for (int e = 0; e < 4; ++e) a4[e] = *(const float4*)(ap + e * 4);
  uint4 w0 = *(const uint4*)wp;
  uint4 w1 = *(const uint4*)(wp + 8);

  for (int k0 = 0; k0 < 512; k0 += 64) {
    const float sc = inv8[k0 >> 6];
    u16 ab16[16];
#pragma unroll
    for (int e = 0; e < 4; ++e) {
      ab16[e * 4 + 0] = f2bf(a4[e].x * sc);
      ab16[e * 4 + 1] = f2bf(a4[e].y * sc);
      ab16[e * 4 + 2] = f2bf(a4[e].z * sc);
      ab16[e * 4 + 3] = f2bf(a4[e].w * sc);
    }
    __syncthreads();
    *(uint4*)&Ab[srow][skc] = *(const uint4*)&ab16[0];
    *(uint4*)&Ab[srow][skc + 8] = *(const uint4*)&ab16[8];
    *(uint4*)&Wb[srow][skc] = w0;
    *(uint4*)&Wb[srow][skc + 8] = w1;
    __syncthreads();
    if (k0 + 64 < 512) {
#pragma unroll
      for (int e = 0; e < 4; ++e) a4[e] = *(const float4*)(ap + k0 + 64 + e * 4);
      w0 = *(const uint4*)(wp + k0 + 64);
      w1 = *(const uint4*)(wp + k0 + 64 + 8);
    }
#pragma unroll
    for (int kk = 0; kk < 2; ++kk) {
      const bf16x8 af = *(const bf16x8*)&Ab[wave * 16 + lrow][kk * 32 + g * 8];
#pragma unroll
      for (int ct = 0; ct < 4; ++ct) {
        const bf16x8 wf = *(const bf16x8*)&Wb[ct * 16 + lrow][kk * 32 + g * 8];
        acc[ct] = __builtin_amdgcn_mfma_f32_16x16x32_bf16(wf, af, acc[ct], 0, 0, 0);
      }
    }
  }
  const int row = r0 + wave * 16 + lrow;
#pragma unroll
  for (int ct = 0; ct < 4; ++ct) {
    const int c = c0 + ct * 16 + g * 4;
    const float4 bb = *(const float4*)&bias2[c];
    const float4 xv = *(const float4*)&x[(size_t)row * 512 + c];
    float4 res;
    res.x = acc[ct][0] + bb.x + xv.x;
    res.y = acc[ct][1] + bb.y + xv.y;
    res.z = acc[ct][2] + bb.z + xv.z;
    res.w = acc[ct][3] + bb.w + xv.w;
    *(float4*)&y[(size_t)row * 512 + c] = res;
  }
}

// K5: out = ((y @ p_w1^T) @ p_w2^T) fused via MFMA. Grid 256.
__global__ __launch_bounds__(256) void k_pout(const float* __restrict__ y,
                                              const float* __restrict__ pw1,
                                              const float* __restrict__ pw2,
                                              float* __restrict__ out) {
  __shared__ __align__(16) u16 yb[16][520];
  __shared__ float tp_part[2][32][17];
  const int r0 = blockIdx.x * 16;
  const int tid = threadIdx.x;
  const int wave = tid >> 6, lane = tid & 63;
  const int lrow = lane & 15, g = lane >> 4;

  for (int rep = 0; rep < 8; ++rep) {
    const int l = rep * 256 + tid;
    const int row = l >> 7, c4 = (l & 127) << 2;
    const float4 v = *(const float4*)&y[(size_t)(r0 + row) * 512 + c4];
    yb[row][c4 + 0] = f2bf(v.x); yb[row][c4 + 1] = f2bf(v.y);
    yb[row][c4 + 2] = f2bf(v.z); yb[row][c4 + 3] = f2bf(v.w);
  }
  __syncthreads();

  {
    const int ct1 = wave & 1, kh = wave >> 1;
    f32x4 acc = {0.f, 0.f, 0.f, 0.f};
#pragma unroll
    for (int ks = 0; ks < 8; ++ks) {
      const int K = kh * 256 + ks * 32 + g * 8;
      union { u16 a[8]; bf16x8 v; } aw;
      const float4 wv0 = *(const float4*)&pw1[(size_t)(ct1 * 16 + lrow) * 512 + K];
      const float4 wv1 = *(const float4*)&pw1[(size_t)(ct1 * 16 + lrow) * 512 + K + 4];
      aw.a[0] = f2bf(wv0.x); aw.a[1] = f2bf(wv0.y);
      aw.a[2] = f2bf(wv0.z); aw.a[3] = f2bf(wv0.w);
      aw.a[4] = f2bf(wv1.x); aw.a[5] = f2bf(wv1.y);
      aw.a[6] = f2bf(wv1.z); aw.a[7] = f2bf(wv1.w);
      const bf16x8 bf = *(const bf16x8*)&yb[lrow][K];
      acc = __builtin_amdgcn_mfma_f32_16x16x32_bf16(aw.v, bf, acc, 0, 0, 0);
    }
#pragma unroll
    for (int j = 0; j < 4; ++j)
      tp_part[kh][ct1 * 16 + g * 4 + j][lrow] = acc[j];
  }
  __syncthreads();

  union { u16 a[8]; bf16x8 v; } bq;
#pragma unroll
  for (int i = 0; i < 8; ++i) {
    const int k = g * 8 + i;
    bq.a[i] = f2bf(tp_part[0][k][lrow] + tp_part[1][k][lrow]);
  }

#pragma unroll
  for (int t = 0; t < 8; ++t) {
    const int ct = wave * 8 + t;
    union { u16 a[8]; bf16x8 v; } aw;
    const float4 wv0 = *(const float4*)&pw2[(size_t)(ct * 16 + lrow) * 32 + g * 8];
    const float4 wv1 = *(const float4*)&pw2[(size_t)(ct * 16 + lrow) * 32 + g * 8 + 4];
    aw.a[0] = f2bf(wv0.x); aw.a[1] = f2bf(wv0.y);
    aw.a[2] = f2bf(wv0.z); aw.a[3] = f2bf(wv0.w);
    aw.a[4] = f2bf(wv1.x); aw.a[5] = f2bf(wv1.y);
    aw.a[6] = f2bf(wv1.z); aw.a[7] = f2bf(wv1.w);
    f32x4 acc = {0.f, 0.f, 0.f, 0.f};
    acc = __builtin_amdgcn_mfma_f32_16x16x32_bf16(aw.v, bq.v, acc, 0, 0, 0);
    float4 res;
    res.x = acc[0]; res.y = acc[1]; res.z = acc[2]; res.w = acc[3];
    *(float4*)&out[(size_t)(r0 + lrow) * 512 + ct * 16 + g * 4] = res;
  }
}

extern "C" void kernel_launch(void* const* d_in, const int* in_sizes, int n_in,
                              void* d_out, int out_size, void* d_ws, size_t ws_size,
                              hipStream_t stream) {
  const float* x     = (const float*)d_in[0];
  const float* q_w1  = (const float*)d_in[1];
  const float* q_w2  = (const float*)d_in[2];
  const float* kv_w1 = (const float*)d_in[3];
  const float* kv_w2 = (const float*)d_in[4];
  const float* dw_w  = (const float*)d_in[5];
  const float* dw_b  = (const float*)d_in[6];
  const float* pw_w  = (const float*)d_in[7];
  const float* pw_b  = (const float*)d_in[8];
  const float* p_w1  = (const float*)d_in[9];
  const float* p_w2  = (const float*)d_in[10];
  float* out = (float*)d_out;

  char* ws = (char*)d_ws;
  u16*   t_bf  = (u16*)ws;                               // 4096*96 u16 (786KB)
  float* dsp   = (float*)ws;                             // alias: 2*8*4096 f32 (dead t_bf)
  float* bias2 = (float*)(ws + 786432);                  // 1024 f32
  u16*   pwbf  = (u16*)(ws + 786432 + 4096);             // 512*512 u16 (512KB)
  u16*   qbw   = pwbf + 262144;                          // 2M u16 (4MB)
  u16*   kbw   = qbw + (size_t)HEADS * NFULL * DDIM;     // 2M u16 (4MB)
  float* y     = (float*)qbw;                            // alias over qbw+kbw (8MB)
  float* vh    = (float*)(kbw + (size_t)HEADS * NFULL * DDIM);  // 2M f32 (8MB)
  float* wvf   = vh + (size_t)HEADS * NFULL * DDIM;      // 2M f32 (8MB)

  k_proj1<<<NFULL / 64, 256, 0, stream>>>(x, q_w1, kv_w1, t_bf);
  k_tred<<<66, 256, 0, stream>>>(pw_w, dw_w, dw_b, pw_b, bias2, pwbf);
  k_proj2<<<(NFULL / 64) * 12, 256, 0, stream>>>(t_bf, q_w2, kv_w2, qbw, kbw, vh);
  k_attn<<<2 * HEADS * (NFULL / 64), 256, 0, stream>>>(qbw, kbw, vh, wvf, dsp);
  k_dyn<<<(NFULL / 64) * 8, 256, 0, stream>>>(wvf, x, pwbf, bias2, dsp, y);
  k_pout<<<NFULL / 16, 256, 0, stream>>>(y, p_w1, p_w2, out);
}

// Round 9
// 88.980 us; speedup vs baseline: 1.5623x; 1.3273x over previous
//
#include <hip/hip_runtime.h>

#define NFULL 4096
#define CDIM  512
#define HEADS 8
#define DDIM  64

typedef unsigned short u16;
typedef short bf16x8 __attribute__((ext_vector_type(8)));
typedef float f32x4 __attribute__((ext_vector_type(4)));

// Hardware exp2: single trans-pipe instruction (libm exp2f w/o fast-math is a
// ~9-instr VALU sequence -> was 50% VALUBusy in k_attn).
#if __has_builtin(__builtin_amdgcn_exp2f)
__device__ __forceinline__ float exp2_hw(float x) { return __builtin_amdgcn_exp2f(x); }
#else
__device__ __forceinline__ float exp2_hw(float x) {
  float r;
  asm volatile("v_exp_f32 %0, %1\n\ts_nop 1" : "=v"(r) : "v"(x));
  return r;
}
#endif
#define EXP2(x) exp2_hw(x)

// q pre-scaled by SCALE * log2(e) so exp(s) == exp2(s').
#define QSCALE 11.541560327111707f  // 8 * 1.4426950408889634

__device__ __forceinline__ float dot4(float4 a, float4 b) {
  return a.x * b.x + a.y * b.y + a.z * b.z + a.w * b.w;
}

__device__ __forceinline__ u16 f2bf(float x) {  // RNE f32 -> bf16 bits
  union { float f; unsigned u; } v; v.f = x;
  unsigned r = v.u + 0x7fffu + ((v.u >> 16) & 1u);
  return (u16)(r >> 16);
}

// K1 (fused): blocks 0..63: t_bf = bf16(x @ [q_w1;kv_w1]^T) via MFMA.
// Blocks 64..65: bias2 = dw_b@pw_w^T + pw_b. Blocks 66..129: pwbf = bf16(pw_w*dw_w).
__global__ __launch_bounds__(256) void k_pre(const float* __restrict__ x,
                                             const float* __restrict__ qw1,
                                             const float* __restrict__ kvw1,
                                             u16* __restrict__ t_bf,
                                             const float* __restrict__ pww,
                                             const float* __restrict__ dww,
                                             const float* __restrict__ dwb,
                                             const float* __restrict__ pwb,
                                             float* __restrict__ bias2,
                                             u16* __restrict__ pwbf) {
  __shared__ __align__(16) u16 Xs[64][72];
  __shared__ __align__(16) u16 Ws[96][72];
  const int tid = threadIdx.x;
  if (blockIdx.x >= 64) {
    const int b = blockIdx.x - 64;
    if (b < 2) {
      const int c = b * 256 + tid;
      float acc = 0.f;
      for (int e = 0; e < 512; e += 4)
        acc += dot4(*(const float4*)&pww[(size_t)c * 512 + e], *(const float4*)&dwb[e]);
      bias2[c] = acc + pwb[c];
    } else {
      const int base = (b - 2) * 4096 + tid * 16;
      const int e0 = base & 511;
      u16 o[16];
#pragma unroll
      for (int q = 0; q < 4; ++q) {
        const float4 w = *(const float4*)&pww[base + q * 4];
        const float4 d = *(const float4*)&dww[e0 + q * 4];
        o[q * 4 + 0] = f2bf(w.x * d.x); o[q * 4 + 1] = f2bf(w.y * d.y);
        o[q * 4 + 2] = f2bf(w.z * d.z); o[q * 4 + 3] = f2bf(w.w * d.w);
      }
      *(uint4*)&pwbf[base] = *(const uint4*)&o[0];
      *(uint4*)&pwbf[base + 8] = *(const uint4*)&o[8];
    }
    return;
  }

  const int r0 = blockIdx.x * 64;
  const int wave = tid >> 6, lane = tid & 63;
  const int lrow = lane & 15, g = lane >> 4;

  f32x4 acc[6];
#pragma unroll
  for (int sub = 0; sub < 6; ++sub) acc[sub] = (f32x4){0.f, 0.f, 0.f, 0.f};

  for (int k0 = 0; k0 < 512; k0 += 64) {
    __syncthreads();
    {  // stage X: 64 rows x 64 k -> bf16
      const int row = tid >> 2, c16 = (tid & 3) * 16;
      const float* __restrict__ src = x + (size_t)(r0 + row) * 512 + k0 + c16;
      u16 tmp[16];
#pragma unroll
      for (int q = 0; q < 4; ++q) {
        const float4 v = *(const float4*)(src + q * 4);
        tmp[q * 4 + 0] = f2bf(v.x); tmp[q * 4 + 1] = f2bf(v.y);
        tmp[q * 4 + 2] = f2bf(v.z); tmp[q * 4 + 3] = f2bf(v.w);
      }
      *(uint4*)&Xs[row][c16] = *(const uint4*)&tmp[0];
      *(uint4*)&Xs[row][c16 + 8] = *(const uint4*)&tmp[8];
    }
    for (int u = tid; u < 384; u += 256) {  // stage W: 96 cols x 64 k
      const int c = u >> 2, c16 = (u & 3) * 16;
      const float* __restrict__ src =
          (c < 32 ? qw1 + (size_t)c * 512 : kvw1 + (size_t)(c - 32) * 512) + k0 + c16;
      u16 tmp[16];
#pragma unroll
      for (int q = 0; q < 4; ++q) {
        const float4 v = *(const float4*)(src + q * 4);
        tmp[q * 4 + 0] = f2bf(v.x); tmp[q * 4 + 1] = f2bf(v.y);
        tmp[q * 4 + 2] = f2bf(v.z); tmp[q * 4 + 3] = f2bf(v.w);
      }
      *(uint4*)&Ws[c][c16] = *(const uint4*)&tmp[0];
      *(uint4*)&Ws[c][c16 + 8] = *(const uint4*)&tmp[8];
    }
    __syncthreads();
    const bf16x8 a0 = *(const bf16x8*)&Xs[wave * 16 + lrow][g * 8];
    const bf16x8 a1 = *(const bf16x8*)&Xs[wave * 16 + lrow][32 + g * 8];
#pragma unroll
    for (int sub = 0; sub < 6; ++sub) {
      const bf16x8 b0 = *(const bf16x8*)&Ws[sub * 16 + lrow][g * 8];
      const bf16x8 b1 = *(const bf16x8*)&Ws[sub * 16 + lrow][32 + g * 8];
      acc[sub] = __builtin_amdgcn_mfma_f32_16x16x32_bf16(a0, b0, acc[sub], 0, 0, 0);
      acc[sub] = __builtin_amdgcn_mfma_f32_16x16x32_bf16(a1, b1, acc[sub], 0, 0, 0);
    }
  }
#pragma unroll
  for (int sub = 0; sub < 6; ++sub)
#pragma unroll
    for (int j = 0; j < 4; ++j)
      t_bf[(size_t)(r0 + wave * 16 + g * 4 + j) * 96 + sub * 16 + lrow] = f2bf(acc[sub][j]);
}

// K2: q/k/v projections via MFMA. Grid 768 = 64 row-blocks x 12 col-blocks.
__global__ __launch_bounds__(256) void k_proj2(const u16* __restrict__ t_bf,
                                               const float* __restrict__ qw2,
                                               const float* __restrict__ kvw2,
                                               u16* __restrict__ qb,
                                               u16* __restrict__ kb,
                                               float* __restrict__ vh) {
  __shared__ __align__(16) u16 Ts[64][72];
  __shared__ __align__(16) u16 Wsh[128][72];
  const int cb = blockIdx.x % 12;
  const int r0 = (blockIdx.x / 12) * 64;
  const int tid = threadIdx.x;
  const int wave = tid >> 6, lane = tid & 63;
  const int lrow = lane & 15, g = lane >> 4;
  const bool isq = cb < 4;
  const int c0 = isq ? cb * 128 : 512 + (cb - 4) * 128;

  for (int u = tid; u < 512; u += 256) {
    const int row = u >> 3, ch = (u & 7) * 8;
    uint4 v = {0u, 0u, 0u, 0u};
    if (isq) {
      if (ch < 32) v = *(const uint4*)&t_bf[(size_t)(r0 + row) * 96 + ch];
    } else {
      v = *(const uint4*)&t_bf[(size_t)(r0 + row) * 96 + 32 + ch];
    }
    *(uint4*)&Ts[row][ch] = v;
  }
  if (isq) {
    for (int u = tid; u < 1024; u += 256) {
      const int col = u >> 3, cf = (u & 7) * 4;
      const float4 v = *(const float4*)&qw2[(size_t)(c0 + col) * 32 + cf];
      u16 tmp[4] = {f2bf(v.x), f2bf(v.y), f2bf(v.z), f2bf(v.w)};
      *(uint2*)&Wsh[col][cf] = *(const uint2*)&tmp[0];
    }
    for (int u = tid; u < 512; u += 256) {
      const int col = u >> 2, ch = 32 + (u & 3) * 8;
      const uint4 z = {0u, 0u, 0u, 0u};
      *(uint4*)&Wsh[col][ch] = z;
    }
  } else {
    for (int u = tid; u < 2048; u += 256) {
      const int col = u >> 4, cf = (u & 15) * 4;
      const float4 v = *(const float4*)&kvw2[(size_t)(c0 - 512 + col) * 64 + cf];
      u16 tmp[4] = {f2bf(v.x), f2bf(v.y), f2bf(v.z), f2bf(v.w)};
      *(uint2*)&Wsh[col][cf] = *(const uint2*)&tmp[0];
    }
  }
  __syncthreads();

  const bf16x8 a0 = *(const bf16x8*)&Ts[wave * 16 + lrow][g * 8];
  const bf16x8 a1 = *(const bf16x8*)&Ts[wave * 16 + lrow][32 + g * 8];
#pragma unroll
  for (int sub = 0; sub < 8; ++sub) {
    const bf16x8 b0 = *(const bf16x8*)&Wsh[sub * 16 + lrow][g * 8];
    const bf16x8 b1 = *(const bf16x8*)&Wsh[sub * 16 + lrow][32 + g * 8];
    f32x4 acc = {0.f, 0.f, 0.f, 0.f};
    acc = __builtin_amdgcn_mfma_f32_16x16x32_bf16(a0, b0, acc, 0, 0, 0);
    acc = __builtin_amdgcn_mfma_f32_16x16x32_bf16(a1, b1, acc, 0, 0, 0);
    const int colg = c0 + sub * 16 + lrow;
#pragma unroll
    for (int j = 0; j < 4; ++j) {
      const int n = r0 + wave * 16 + g * 4 + j;
      if (colg < 512) {
        qb[((size_t)(colg >> 6) * NFULL + n) * 64 + (colg & 63)] = f2bf(acc[j] * QSCALE);
      } else if (colg < 1024) {
        const int c2 = colg - 512;
        kb[((size_t)(c2 >> 6) * NFULL + n) * 64 + (c2 & 63)] = f2bf(acc[j]);
      } else {
        const int c2 = colg - 1024;
        vh[((size_t)(c2 >> 6) * NFULL + n) * 64 + (c2 & 63)] = acc[j];
      }
    }
  }
}

// K3: attention. Block (h, qt, s): 64 queries, keys [s*2048,+2048) in 32 tiles.
// Each wave stages its own 16 rows per tile via global_load_lds into a 4-deep
// circular swizzled LDS buffer (counted vmcnt, no main-loop barriers).
__global__ __launch_bounds__(256, 4) void k_attn(const u16* __restrict__ qb,
                                                 const u16* __restrict__ kb,
                                                 const float* __restrict__ vh,
                                                 float* __restrict__ wv,
                                                 float* __restrict__ dsp) {
  __shared__ __align__(16) u16 KB[4][64][64];  // 32 KB, rows XOR-swizzled
  __shared__ float P_lds[4][16][17];
  __shared__ float Ds[4][4][16];

  const int h = blockIdx.x & 7;            // XCD affinity: head == XCD
  const int qt = (blockIdx.x >> 3) & 63;
  const int s = blockIdx.x >> 9;
  const int q0 = qt * 64;
  const int tid = threadIdx.x;
  const int wave = tid >> 6, lane = tid & 63;
  const int lrow = lane & 15, g = lane >> 4;

  const u16* __restrict__ Qg = qb + ((size_t)h * NFULL + q0) * 64;
  const u16* __restrict__ Kg = kb + ((size_t)h * NFULL + (size_t)s * 2048) * 64;

  bf16x8 qf[4][2];
#pragma unroll
  for (int f = 0; f < 4; ++f) {
    qf[f][0] = *(const bf16x8*)&Qg[(f * 16 + lrow) * 64 + g * 8];
    qf[f][1] = *(const bf16x8*)&Qg[(f * 16 + lrow) * 64 + 32 + g * 8];
  }

  const int srow8 = lane >> 3;
  const int scol = ((lane & 7) ^ srow8) << 3;

#define STAGE(T, B)                                                           \
  do {                                                                        \
    const u16* tb_ = Kg + (size_t)(T) * 64 * 64;                              \
    {                                                                         \
      const u16* src_ = tb_ + (wave * 16 + srow8) * 64 + scol;                \
      u16* dst_ = &KB[(B)][wave * 16][0];                                     \
      __builtin_amdgcn_global_load_lds(                                       \
          (const __attribute__((address_space(1))) unsigned*)src_,            \
          (__attribute__((address_space(3))) unsigned*)dst_, 16, 0, 0);       \
    }                                                                         \
    {                                                                         \
      const u16* src_ = tb_ + (wave * 16 + 8 + srow8) * 64 + scol;            \
      u16* dst_ = &KB[(B)][wave * 16][0] + 512;                               \
      __builtin_amdgcn_global_load_lds(                                       \
          (const __attribute__((address_space(1))) unsigned*)src_,            \
          (__attribute__((address_space(3))) unsigned*)dst_, 16, 0, 0);       \
    }                                                                         \
  } while (0)

  const int rsw = wave * 16 + lrow;
  const int x0 = (g ^ (lrow & 7)) * 8;
  const int x1 = ((g + 4) ^ (lrow & 7)) * 8;

  float dsum[4] = {0.f, 0.f, 0.f, 0.f};
  const bool dg = (s == (qt >> 5));
  const int tdiag = qt & 31;

  STAGE(0, 0); STAGE(1, 1); STAGE(2, 2);

  for (int t = 0; t < 32; ++t) {
    const int b = t & 3;
    if (t + 3 < 32) STAGE(t + 3, (t + 3) & 3);
    if (t < 29)       asm volatile("s_waitcnt vmcnt(6)" ::: "memory");
    else if (t == 29) asm volatile("s_waitcnt vmcnt(4)" ::: "memory");
    else if (t == 30) asm volatile("s_waitcnt vmcnt(2)" ::: "memory");
    else              asm volatile("s_waitcnt vmcnt(0)" ::: "memory");

    const bf16x8 kf0 = *(const bf16x8*)&KB[b][rsw][x0];
    const bf16x8 kf1 = *(const bf16x8*)&KB[b][rsw][x1];
    f32x4 a[4];
    __builtin_amdgcn_s_setprio(1);
#pragma unroll
    for (int f = 0; f < 4; ++f) {
      f32x4 t4 = {0.f, 0.f, 0.f, 0.f};
      t4 = __builtin_amdgcn_mfma_f32_16x16x32_bf16(kf0, qf[f][0], t4, 0, 0, 0);
      t4 = __builtin_amdgcn_mfma_f32_16x16x32_bf16(kf1, qf[f][1], t4, 0, 0, 0);
      a[f] = t4;
    }
    __builtin_amdgcn_s_setprio(0);
    const bool isd = dg && (t == tdiag);
#pragma unroll
    for (int f = 0; f < 4; ++f) {
      const float e0 = EXP2(a[f][0]);
      const float e1 = EXP2(a[f][1]);
      const float e2 = EXP2(a[f][2]);
      const float e3 = EXP2(a[f][3]);
      dsum[f] += (e0 + e1) + (e2 + e3);
      if (isd && f == wave) {
        const int rr = g * 4;
        P_lds[wave][rr + 0][lrow] = (rr + 0 <= lrow) ? e0 : 0.f;
        P_lds[wave][rr + 1][lrow] = (rr + 1 <= lrow) ? e1 : 0.f;
        P_lds[wave][rr + 2][lrow] = (rr + 2 <= lrow) ? e2 : 0.f;
        P_lds[wave][rr + 3][lrow] = (rr + 3 <= lrow) ? e3 : 0.f;
      }
    }
  }
#undef STAGE

#pragma unroll
  for (int f = 0; f < 4; ++f) {
    dsum[f] += __shfl_xor(dsum[f], 16);
    dsum[f] += __shfl_xor(dsum[f], 32);
  }
  if (g == 0) {
#pragma unroll
    for (int f = 0; f < 4; ++f) Ds[wave][f][lrow] = dsum[f];
  }
  __syncthreads();

  if (tid < 64) {
    const int f = tid >> 4, r = tid & 15;
    const float den = Ds[0][f][r] + Ds[1][f][r] + Ds[2][f][r] + Ds[3][f][r];
    dsp[((size_t)s * HEADS + h) * NFULL + q0 + f * 16 + r] = den;
  }

  if (dg) {
    const float* __restrict__ V =
        vh + ((size_t)h * NFULL + q0 + wave * 16) * 64 + g * 16;
    float o[16];
#pragma unroll
    for (int dd = 0; dd < 16; ++dd) o[dd] = 0.f;
#pragma unroll
    for (int k = 0; k < 16; ++k) {
      const float p = P_lds[wave][k][lrow];
      const float4 v0 = *(const float4*)&V[k * 64 + 0];
      const float4 v1 = *(const float4*)&V[k * 64 + 4];
      const float4 v2 = *(const float4*)&V[k * 64 + 8];
      const float4 v3 = *(const float4*)&V[k * 64 + 12];
      o[0] += p * v0.x;  o[1] += p * v0.y;  o[2] += p * v0.z;  o[3] += p * v0.w;
      o[4] += p * v1.x;  o[5] += p * v1.y;  o[6] += p * v1.z;  o[7] += p * v1.w;
      o[8] += p * v2.x;  o[9] += p * v2.y;  o[10] += p * v2.z; o[11] += p * v2.w;
      o[12] += p * v3.x; o[13] += p * v3.y; o[14] += p * v3.z; o[15] += p * v3.w;
    }
    float* __restrict__ op =
        wv + (size_t)(q0 + wave * 16 + lrow) * CDIM + h * 64 + g * 16;
#pragma unroll
    for (int c4 = 0; c4 < 4; ++c4) {
      float4 r;
      r.x = o[c4 * 4 + 0]; r.y = o[c4 * 4 + 1];
      r.z = o[c4 * 4 + 2]; r.w = o[c4 * 4 + 3];
      *(float4*)&op[c4 * 4] = r;
    }
  }
}

// K4: y = normalize(wv) @ pwbf^T + bias2 + x; denom = sum of 2 dsp splits.
__global__ __launch_bounds__(256) void k_dyn(const float* __restrict__ wv,
                                             const float* __restrict__ x,
                                             const u16* __restrict__ pwbf,
                                             const float* __restrict__ bias2,
                                             const float* __restrict__ dsp,
                                             float* __restrict__ y) {
  __shared__ __align__(16) u16 Ab[64][72];
  __shared__ __align__(16) u16 Wb[64][72];
  const int rb = blockIdx.x >> 3, cb = blockIdx.x & 7;
  const int r0 = rb * 64, c0 = cb * 64;
  const int tid = threadIdx.x;
  const int wave = tid >> 6, lane = tid & 63;
  const int lrow = lane & 15, g = lane >> 4;
  const int srow = tid >> 2;
  const int skc = (tid & 3) * 16;

  float inv8[8];
#pragma unroll
  for (int hh = 0; hh < 8; ++hh) {
    const size_t base = (size_t)hh * NFULL + r0 + srow;
    inv8[hh] = 1.0f / (dsp[base] + dsp[(size_t)8 * NFULL + base]);
  }

  f32x4 acc[4];
#pragma unroll
  for (int ct = 0; ct < 4; ++ct) acc[ct] = (f32x4){0.f, 0.f, 0.f, 0.f};

  const float* __restrict__ ap = wv + (size_t)(r0 + srow) * 512 + skc;
  const u16* __restrict__ wp = pwbf + (size_t)(c0 + srow) * 512 + skc;
  float4 a4[4];
#pragma unroll
  for (int e = 0; e < 4; ++e) a4[e] = *(const float4*)(ap + e * 4);
  uint4 w0 = *(const uint4*)wp;
  uint4 w1 = *(const uint4*)(wp + 8);

  for (int k0 = 0; k0 < 512; k0 += 64) {
    const float sc = inv8[k0 >> 6];
    u16 ab16[16];
#pragma unroll
    for (int e = 0; e < 4; ++e) {
      ab16[e * 4 + 0] = f2bf(a4[e].x * sc);
      ab16[e * 4 + 1] = f2bf(a4[e].y * sc);
      ab16[e * 4 + 2] = f2bf(a4[e].z * sc);
      ab16[e * 4 + 3] = f2bf(a4[e].w * sc);
    }
    __syncthreads();
    *(uint4*)&Ab[srow][skc] = *(const uint4*)&ab16[0];
    *(uint4*)&Ab[srow][skc + 8] = *(const uint4*)&ab16[8];
    *(uint4*)&Wb[srow][skc] = w0;
    *(uint4*)&Wb[srow][skc + 8] = w1;
    __syncthreads();
    if (k0 + 64 < 512) {
#pragma unroll
      for (int e = 0; e < 4; ++e) a4[e] = *(const float4*)(ap + k0 + 64 + e * 4);
      w0 = *(const uint4*)(wp + k0 + 64);
      w1 = *(const uint4*)(wp + k0 + 64 + 8);
    }
#pragma unroll
    for (int kk = 0; kk < 2; ++kk) {
      const bf16x8 af = *(const bf16x8*)&Ab[wave * 16 + lrow][kk * 32 + g * 8];
#pragma unroll
      for (int ct = 0; ct < 4; ++ct) {
        const bf16x8 wf = *(const bf16x8*)&Wb[ct * 16 + lrow][kk * 32 + g * 8];
        acc[ct] = __builtin_amdgcn_mfma_f32_16x16x32_bf16(wf, af, acc[ct], 0, 0, 0);
      }
    }
  }
  const int row = r0 + wave * 16 + lrow;
#pragma unroll
  for (int ct = 0; ct < 4; ++ct) {
    const int c = c0 + ct * 16 + g * 4;
    const float4 bb = *(const float4*)&bias2[c];
    const float4 xv = *(const float4*)&x[(size_t)row * 512 + c];
    float4 res;
    res.x = acc[ct][0] + bb.x + xv.x;
    res.y = acc[ct][1] + bb.y + xv.y;
    res.z = acc[ct][2] + bb.z + xv.z;
    res.w = acc[ct][3] + bb.w + xv.w;
    *(float4*)&y[(size_t)row * 512 + c] = res;
  }
}

// K5: out = ((y @ p_w1^T) @ p_w2^T) fused via MFMA. Grid 256.
__global__ __launch_bounds__(256) void k_pout(const float* __restrict__ y,
                                              const float* __restrict__ pw1,
                                              const float* __restrict__ pw2,
                                              float* __restrict__ out) {
  __shared__ __align__(16) u16 yb[16][520];
  __shared__ float tp_part[2][32][17];
  const int r0 = blockIdx.x * 16;
  const int tid = threadIdx.x;
  const int wave = tid >> 6, lane = tid & 63;
  const int lrow = lane & 15, g = lane >> 4;

  for (int rep = 0; rep < 8; ++rep) {
    const int l = rep * 256 + tid;
    const int row = l >> 7, c4 = (l & 127) << 2;
    const float4 v = *(const float4*)&y[(size_t)(r0 + row) * 512 + c4];
    yb[row][c4 + 0] = f2bf(v.x); yb[row][c4 + 1] = f2bf(v.y);
    yb[row][c4 + 2] = f2bf(v.z); yb[row][c4 + 3] = f2bf(v.w);
  }
  __syncthreads();

  {
    const int ct1 = wave & 1, kh = wave >> 1;
    f32x4 acc = {0.f, 0.f, 0.f, 0.f};
#pragma unroll
    for (int ks = 0; ks < 8; ++ks) {
      const int K = kh * 256 + ks * 32 + g * 8;
      union { u16 a[8]; bf16x8 v; } aw;
      const float4 wv0 = *(const float4*)&pw1[(size_t)(ct1 * 16 + lrow) * 512 + K];
      const float4 wv1 = *(const float4*)&pw1[(size_t)(ct1 * 16 + lrow) * 512 + K + 4];
      aw.a[0] = f2bf(wv0.x); aw.a[1] = f2bf(wv0.y);
      aw.a[2] = f2bf(wv0.z); aw.a[3] = f2bf(wv0.w);
      aw.a[4] = f2bf(wv1.x); aw.a[5] = f2bf(wv1.y);
      aw.a[6] = f2bf(wv1.z); aw.a[7] = f2bf(wv1.w);
      const bf16x8 bf = *(const bf16x8*)&yb[lrow][K];
      acc = __builtin_amdgcn_mfma_f32_16x16x32_bf16(aw.v, bf, acc, 0, 0, 0);
    }
#pragma unroll
    for (int j = 0; j < 4; ++j)
      tp_part[kh][ct1 * 16 + g * 4 + j][lrow] = acc[j];
  }
  __syncthreads();

  union { u16 a[8]; bf16x8 v; } bq;
#pragma unroll
  for (int i = 0; i < 8; ++i) {
    const int k = g * 8 + i;
    bq.a[i] = f2bf(tp_part[0][k][lrow] + tp_part[1][k][lrow]);
  }

#pragma unroll
  for (int t = 0; t < 8; ++t) {
    const int ct = wave * 8 + t;
    union { u16 a[8]; bf16x8 v; } aw;
    const float4 wv0 = *(const float4*)&pw2[(size_t)(ct * 16 + lrow) * 32 + g * 8];
    const float4 wv1 = *(const float4*)&pw2[(size_t)(ct * 16 + lrow) * 32 + g * 8 + 4];
    aw.a[0] = f2bf(wv0.x); aw.a[1] = f2bf(wv0.y);
    aw.a[2] = f2bf(wv0.z); aw.a[3] = f2bf(wv0.w);
    aw.a[4] = f2bf(wv1.x); aw.a[5] = f2bf(wv1.y);
    aw.a[6] = f2bf(wv1.z); aw.a[7] = f2bf(wv1.w);
    f32x4 acc = {0.f, 0.f, 0.f, 0.f};
    acc = __builtin_amdgcn_mfma_f32_16x16x32_bf16(aw.v, bq.v, acc, 0, 0, 0);
    float4 res;
    res.x = acc[0]; res.y = acc[1]; res.z = acc[2]; res.w = acc[3];
    *(float4*)&out[(size_t)(r0 + lrow) * 512 + ct * 16 + g * 4] = res;
  }
}

extern "C" void kernel_launch(void* const* d_in, const int* in_sizes, int n_in,
                              void* d_out, int out_size, void* d_ws, size_t ws_size,
                              hipStream_t stream) {
  const float* x     = (const float*)d_in[0];
  const float* q_w1  = (const float*)d_in[1];
  const float* q_w2  = (const float*)d_in[2];
  const float* kv_w1 = (const float*)d_in[3];
  const float* kv_w2 = (const float*)d_in[4];
  const float* dw_w  = (const float*)d_in[5];
  const float* dw_b  = (const float*)d_in[6];
  const float* pw_w  = (const float*)d_in[7];
  const float* pw_b  = (const float*)d_in[8];
  const float* p_w1  = (const float*)d_in[9];
  const float* p_w2  = (const float*)d_in[10];
  float* out = (float*)d_out;

  char* ws = (char*)d_ws;
  u16*   t_bf  = (u16*)ws;                               // 4096*96 u16 (786KB)
  float* dsp   = (float*)ws;                             // alias: 2*8*4096 f32 (dead t_bf)
  float* bias2 = (float*)(ws + 786432);                  // 1024 f32
  u16*   pwbf  = (u16*)(ws + 786432 + 4096);             // 512*512 u16 (512KB)
  u16*   qbw   = pwbf + 262144;                          // 2M u16 (4MB)
  u16*   kbw   = qbw + (size_t)HEADS * NFULL * DDIM;     // 2M u16 (4MB)
  float* y     = (float*)qbw;                            // alias over qbw+kbw (8MB)
  float* vh    = (float*)(kbw + (size_t)HEADS * NFULL * DDIM);  // 2M f32 (8MB)
  float* wvf   = vh + (size_t)HEADS * NFULL * DDIM;      // 2M f32 (8MB)

  k_pre<<<130, 256, 0, stream>>>(x, q_w1, kv_w1, t_bf, pw_w, dw_w, dw_b, pw_b,
                                 bias2, pwbf);
  k_proj2<<<(NFULL / 64) * 12, 256, 0, stream>>>(t_bf, q_w2, kv_w2, qbw, kbw, vh);
  k_attn<<<2 * HEADS * (NFULL / 64), 256, 0, stream>>>(qbw, kbw, vh, wvf, dsp);
  k_dyn<<<(NFULL / 64) * 8, 256, 0, stream>>>(wvf, x, pwbf, bias2, dsp, y);
  k_pout<<<NFULL / 16, 256, 0, stream>>>(y, p_w1, p_w2, out);
}